// Round 1
// 235.308 us; speedup vs baseline: 1.0186x; 1.0186x over previous
//
#include <hip/hip_runtime.h>
#include <hip/hip_bf16.h>
#include <math.h>

#define N_NODES 50000
#define N_EDGES 1600000
#define IN_FEAT 256
#define HIDDEN 128
#define N_CLASSES 16

#define ECHUNK 8192
#define NCHK 196    // ceil(1600000/8192)
#define NBKT 196    // ceil(50000/256) buckets of 256 nodes
#define BCAP 10240  // per-bucket capacity: mean 8192, std ~90 -> +23 sigma

typedef __attribute__((ext_vector_type(8))) short short8;   // 8 bf16 (A/B frag)
typedef __attribute__((ext_vector_type(4))) float floatx4;  // C/D frag

// bf16 round-to-nearest-even (scalar integer path)
__device__ __forceinline__ unsigned short f2bf(float f) {
    unsigned u = __float_as_uint(f);
    return (unsigned short)((u + 0x7fffu + ((u >> 16) & 1u)) >> 16);
}

// HW packed fp32->bf16x2
__device__ __forceinline__ unsigned pk2bf(float a, float b) {
    __hip_bfloat162 h = __float22bfloat162_rn(make_float2(a, b));
    union { __hip_bfloat162 h; unsigned u; } cv;
    cv.h = h;
    return cv.u;
}

__device__ __forceinline__ float bflo(unsigned u) { return __uint_as_float(u << 16); }
__device__ __forceinline__ float bfhi(unsigned u) { return __uint_as_float(u & 0xffff0000u); }

// ---------------------------------------------------------------------------
// Prep: fixed-capacity buckets. scatter: LDS-count -> 1 global atomic per
// (block,bucket) -> local scatter. Blocks 0..127 also transpose W1 -> w1t.
// ---------------------------------------------------------------------------
__global__ __launch_bounds__(256) void scatter_edges2(const int* __restrict__ src,
                                                      const int* __restrict__ dst,
                                                      int* __restrict__ cursor,   // [256], zeroed
                                                      unsigned int* __restrict__ sorted,
                                                      const float* __restrict__ W1,
                                                      unsigned short* __restrict__ w1t) {
    __shared__ int hloc[256];
    int t = threadIdx.x;
    hloc[t] = 0;
    if (blockIdx.x < HIDDEN)
        w1t[blockIdx.x * IN_FEAT + t] = f2bf(W1[t * HIDDEN + blockIdx.x]);
    __syncthreads();
    int base = blockIdx.x * ECHUNK;
    int end = min(base + ECHUNK, N_EDGES);
    for (int i = base + t; i < end; i += 256)
        atomicAdd(&hloc[dst[i] >> 8], 1);
    __syncthreads();
    int cnt = hloc[t];
    int lbase = t * BCAP + atomicAdd(&cursor[t], cnt);  // block's base in bucket t
    __syncthreads();
    hloc[t] = lbase;  // reuse as local cursor
    __syncthreads();
    for (int i = base + t; i < end; i += 256) {
        int d = dst[i];
        int s = src[i];
        int pos = atomicAdd(&hloc[d >> 8], 1);
        sorted[pos] = ((unsigned)d << 16) | (unsigned)s;
    }
}

__global__ __launch_bounds__(256) void build_csr2(const unsigned int* __restrict__ sorted,
                                                  const int* __restrict__ cursor,
                                                  int* __restrict__ rs,
                                                  int* __restrict__ re,
                                                  float* __restrict__ dis,
                                                  unsigned short* __restrict__ csr_src) {
    __shared__ int cnt[256];
    __shared__ int roff[256];
    int t = threadIdx.x;
    int bkt = blockIdx.x;
    int ebase = bkt * BCAP;
    int eend = ebase + cursor[bkt];
    cnt[t] = 0;
    __syncthreads();
    for (int i = ebase + t; i < eend; i += 256)
        atomicAdd(&cnt[(sorted[i] >> 16) & 255], 1);
    __syncthreads();
    int v = cnt[t];
    roff[t] = v;
    __syncthreads();
    for (int off = 1; off < 256; off <<= 1) {
        int x = (t >= off) ? roff[t - off] : 0;
        __syncthreads();
        roff[t] += x;
        __syncthreads();
    }
    int excl = roff[t] - v;
    int node = bkt * 256 + t;
    if (node < N_NODES) {
        rs[node] = ebase + excl;
        re[node] = ebase + excl + v;
        dis[node] = 1.0f / sqrtf((float)(v + 1));  // +1 self loop
    }
    __syncthreads();
    cnt[t] = ebase + excl;  // reuse as cursor
    __syncthreads();
    for (int i = ebase + t; i < eend; i += 256) {
        unsigned e = sorted[i];
        int pos = atomicAdd(&cnt[(e >> 16) & 255], 1);
        csr_src[pos] = (unsigned short)(e & 0xffffu);
    }
}

// ---------------------------------------------------------------------------
// GEMM1 via MFMA with LDS-staged A (global_load_lds, width 16).
// Block 64 rows x 128 cols, 4 waves (2x2); wave = 32 rows x 64 cols.
// Output layout is SLICE-MAJOR: g1[slice][node][16 dwords] with slice =
// col>>5, so each 32-feature slice is a contiguous 3.2 MB plane (fits one
// XCD's 4 MB L2; slices never share a 128B L2 line).
// ---------------------------------------------------------------------------
#define XCH 260   // dwords per 8-row chunk: 8*32 + 4 pad

__global__ __launch_bounds__(256) void gemm1_mfma(const float* __restrict__ x,
                                                  const unsigned short* __restrict__ w1t,
                                                  const float* __restrict__ dis,
                                                  unsigned int* __restrict__ g1) {
    __shared__ float xs[2][8 * XCH];   // 2 x 8320 B
    int tid = threadIdx.x;
    int w = tid >> 6;
    int lane = tid & 63;
    int quad = lane >> 4;
    int c = lane & 15;
    int row_base = blockIdx.x * 64;
    int wrow = (w >> 1) * 32;        // wave's row offset in tile
    int col_base = (w & 1) * 64;

    // staging: wave w stages chunks 2w, 2w+1 (rows 16w..16w+15 of the tile)
    int st_row = min(row_base + 16 * w + (lane >> 3), N_NODES - 1);       // chunk 2w
    int st_row2 = min(row_base + 16 * w + 8 + (lane >> 3), N_NODES - 1);  // chunk 2w+1
    const float* gp1 = x + (size_t)st_row * IN_FEAT + (lane & 7) * 4;
    const float* gp2 = x + (size_t)st_row2 * IN_FEAT + (lane & 7) * 4;

    floatx4 acc[2][4] = {};
    const unsigned short* bp[4];
#pragma unroll
    for (int nt = 0; nt < 4; ++nt)
        bp[nt] = w1t + (size_t)(col_base + nt * 16 + c) * IN_FEAT + quad * 8;

    // A-frag ds_read offsets (dwords) for rt=0,1
    int dwoff[2];
#pragma unroll
    for (int rt = 0; rt < 2; ++rt) {
        int rit = wrow + rt * 16 + c;
        dwoff[rt] = (rit >> 3) * XCH + (rit & 7) * 32 + quad * 8;
    }

#define STAGE(buf, k0)                                                                  \
    do {                                                                                \
        __builtin_amdgcn_global_load_lds(                                               \
            (const __attribute__((address_space(1))) void*)(gp1 + (k0)),                \
            (__attribute__((address_space(3))) void*)&xs[buf][(2 * w) * XCH], 16, 0, 0);\
        __builtin_amdgcn_global_load_lds(                                               \
            (const __attribute__((address_space(1))) void*)(gp2 + (k0)),                \
            (__attribute__((address_space(3))) void*)&xs[buf][(2 * w + 1) * XCH], 16, 0, 0);\
    } while (0)

    STAGE(0, 0);
    __syncthreads();

    int buf = 0;
#pragma unroll
    for (int kk = 0; kk < 8; ++kk) {
        if (kk < 7) STAGE(buf ^ 1, (kk + 1) * 32);
        // B frags for this k-step (global, L2-hot)
        short8 b[4];
#pragma unroll
        for (int nt = 0; nt < 4; ++nt)
            b[nt] = *(const short8*)(bp[nt] + kk * 32);
        // A frags from LDS, convert fp32 -> bf16
        short8 a[2];
#pragma unroll
        for (int rt = 0; rt < 2; ++rt) {
            float4 f0 = *(const float4*)&xs[buf][dwoff[rt]];
            float4 f1 = *(const float4*)&xs[buf][dwoff[rt] + 4];
            union { short8 s; unsigned u[4]; } au;
            au.u[0] = pk2bf(f0.x, f0.y);
            au.u[1] = pk2bf(f0.z, f0.w);
            au.u[2] = pk2bf(f1.x, f1.y);
            au.u[3] = pk2bf(f1.z, f1.w);
            a[rt] = au.s;
        }
#pragma unroll
        for (int rt = 0; rt < 2; ++rt)
#pragma unroll
            for (int nt = 0; nt < 4; ++nt)
                acc[rt][nt] = __builtin_amdgcn_mfma_f32_16x16x32_bf16(a[rt], b[nt], acc[rt][nt], 0, 0, 0);
        __syncthreads();   // drains stage vmcnt + protects buf reuse
        buf ^= 1;
    }
#undef STAGE

    // Epilogue: dis scale, pair adjacent cols via shfl, pack bf16x2, store
    // into slice-major layout. C/D layout: col = lane&15, row = quad*4 + reg.
    bool evenlane = (lane & 1) == 0;
#pragma unroll
    for (int rt = 0; rt < 2; ++rt) {
#pragma unroll
        for (int reg = 0; reg < 4; ++reg) {
            int row = row_base + wrow + rt * 16 + quad * 4 + reg;
            float dv = dis[min(row, N_NODES - 1)];
#pragma unroll
            for (int nt = 0; nt < 4; ++nt) {
                float v = acc[rt][nt][reg] * dv;
                float vo = __shfl_xor(v, 1);
                if (evenlane && row < N_NODES) {
                    unsigned pkd = (unsigned)f2bf(v) | ((unsigned)f2bf(vo) << 16);
                    int col = col_base + nt * 16 + c;  // even
                    g1[(size_t)(col >> 5) * (N_NODES * 16) + (size_t)row * 16 + ((col & 31) >> 1)] = pkd;
                }
            }
        }
    }
}

// ---------------------------------------------------------------------------
// Aggregation 1 + bias + ReLU + per-slice GEMM2 partial, feature-sliced and
// XCD-pinned. Grid = 196 buckets x 16; blockIdx&7 selects XCD (round-robin
// heuristic) -> slice = (blockIdx&7)>>1, so each XCD only gathers from one
// 3.2 MB g1 plane (L2-resident). Block covers 64 nodes (quarter bucket);
// 32 8-lane groups each own a node: per edge one 64B gather (uint2/lane).
// GEMM2 partial p[c] = sum_{f in slice} relu(...)[f]*W2[f][c] -> g2p plane.
// ---------------------------------------------------------------------------
__global__ __launch_bounds__(256) void agg1_sliced(const uint2* __restrict__ g1,
                                                   const int* __restrict__ rs,
                                                   const int* __restrict__ re,
                                                   const unsigned short* __restrict__ csr_src,
                                                   const float* __restrict__ dis,
                                                   const float* __restrict__ b1,
                                                   const float* __restrict__ W2,
                                                   float* __restrict__ g2p) {
    __shared__ float w2s[32 * 16];      // this slice's W2 rows (2 KB)
    __shared__ float rbuf[4][8][36];    // per wave/group r vector, padded: 16B-aligned rows, conflict-free
    int tid = threadIdx.x;
    int bi = blockIdx.x;
    int bucket = bi >> 4;               // 196
    int xcd = bi & 7;
    int slice = xcd >> 1;               // XCD pair {2s,2s+1} -> slice s
    int quarter = ((bi >> 3) & 1) * 2 + (xcd & 1);

    for (int i = tid; i < 512; i += 256) w2s[i] = W2[slice * 512 + i];
    __syncthreads();

    int wave = tid >> 6, lane = tid & 63;
    int g = lane >> 3, m = lane & 7;    // group g owns a node; lane m covers feats 4m..4m+3 of slice
    const uint2* plane = g1 + (size_t)slice * (N_NODES * 8);
    float* gp = g2p + (size_t)slice * ((size_t)N_NODES * 16);
    int nbase = bucket * 256 + quarter * 64 + (wave * 8 + g) * 2;

#pragma unroll 1
    for (int nn = 0; nn < 2; ++nn) {
        int node = nbase + nn;
        if (node >= N_NODES) continue;
        // self loop (g1 already carries dis[src] scaling)
        uint2 su = plane[(size_t)node * 8 + m];
        float s0 = bflo(su.x), s1 = bfhi(su.x), s2 = bflo(su.y), s3 = bfhi(su.y);
        int e = rs[node], e1v = re[node];
        for (; e + 8 <= e1v; e += 8) {
            int i0 = csr_src[e + 0], i1 = csr_src[e + 1];
            int i2 = csr_src[e + 2], i3 = csr_src[e + 3];
            int i4 = csr_src[e + 4], i5 = csr_src[e + 5];
            int i6 = csr_src[e + 6], i7 = csr_src[e + 7];
            uint2 u0 = plane[(size_t)i0 * 8 + m];
            uint2 u1 = plane[(size_t)i1 * 8 + m];
            uint2 u2 = plane[(size_t)i2 * 8 + m];
            uint2 u3 = plane[(size_t)i3 * 8 + m];
            uint2 u4 = plane[(size_t)i4 * 8 + m];
            uint2 u5 = plane[(size_t)i5 * 8 + m];
            uint2 u6 = plane[(size_t)i6 * 8 + m];
            uint2 u7 = plane[(size_t)i7 * 8 + m];
            s0 += bflo(u0.x); s1 += bfhi(u0.x); s2 += bflo(u0.y); s3 += bfhi(u0.y);
            s0 += bflo(u1.x); s1 += bfhi(u1.x); s2 += bflo(u1.y); s3 += bfhi(u1.y);
            s0 += bflo(u2.x); s1 += bfhi(u2.x); s2 += bflo(u2.y); s3 += bfhi(u2.y);
            s0 += bflo(u3.x); s1 += bfhi(u3.x); s2 += bflo(u3.y); s3 += bfhi(u3.y);
            s0 += bflo(u4.x); s1 += bfhi(u4.x); s2 += bflo(u4.y); s3 += bfhi(u4.y);
            s0 += bflo(u5.x); s1 += bfhi(u5.x); s2 += bflo(u5.y); s3 += bfhi(u5.y);
            s0 += bflo(u6.x); s1 += bfhi(u6.x); s2 += bflo(u6.y); s3 += bfhi(u6.y);
            s0 += bflo(u7.x); s1 += bfhi(u7.x); s2 += bflo(u7.y); s3 += bfhi(u7.y);
        }
        if (e < e1v) {  // predicated tail chunk (<=7 edges), clamped idx loads
            int last = e1v - 1;
            int i0 = csr_src[e];
            int i1 = csr_src[min(e + 1, last)];
            int i2 = csr_src[min(e + 2, last)];
            int i3 = csr_src[min(e + 3, last)];
            int i4 = csr_src[min(e + 4, last)];
            int i5 = csr_src[min(e + 5, last)];
            int i6 = csr_src[min(e + 6, last)];
            uint2 u0 = plane[(size_t)i0 * 8 + m];
            uint2 u1 = plane[(size_t)i1 * 8 + m];
            uint2 u2 = plane[(size_t)i2 * 8 + m];
            uint2 u3 = plane[(size_t)i3 * 8 + m];
            uint2 u4 = plane[(size_t)i4 * 8 + m];
            uint2 u5 = plane[(size_t)i5 * 8 + m];
            uint2 u6 = plane[(size_t)i6 * 8 + m];
            s0 += bflo(u0.x); s1 += bfhi(u0.x); s2 += bflo(u0.y); s3 += bfhi(u0.y);
            if (e + 1 < e1v) { s0 += bflo(u1.x); s1 += bfhi(u1.x); s2 += bflo(u1.y); s3 += bfhi(u1.y); }
            if (e + 2 < e1v) { s0 += bflo(u2.x); s1 += bfhi(u2.x); s2 += bflo(u2.y); s3 += bfhi(u2.y); }
            if (e + 3 < e1v) { s0 += bflo(u3.x); s1 += bfhi(u3.x); s2 += bflo(u3.y); s3 += bfhi(u3.y); }
            if (e + 4 < e1v) { s0 += bflo(u4.x); s1 += bfhi(u4.x); s2 += bflo(u4.y); s3 += bfhi(u4.y); }
            if (e + 5 < e1v) { s0 += bflo(u5.x); s1 += bfhi(u5.x); s2 += bflo(u5.y); s3 += bfhi(u5.y); }
            if (e + 6 < e1v) { s0 += bflo(u6.x); s1 += bfhi(u6.x); s2 += bflo(u6.y); s3 += bfhi(u6.y); }
        }
        float dv = dis[node];
        float4 bb = *(const float4*)&b1[slice * 32 + 4 * m];
        float4 r;
        r.x = fmaxf(fmaf(dv, s0, bb.x), 0.f);
        r.y = fmaxf(fmaf(dv, s1, bb.y), 0.f);
        r.z = fmaxf(fmaf(dv, s2, bb.z), 0.f);
        r.w = fmaxf(fmaf(dv, s3, bb.w), 0.f);
        // intra-wave LDS redistribute (DS pipe is in-order per wave; fence the
        // compiler so it can't hoist the reads above the write)
        *(float4*)&rbuf[wave][g][4 * m] = r;
        __builtin_amdgcn_sched_barrier(0);
        // GEMM2 partial: lane m computes classes 2m, 2m+1 over all 32 feats
        float p0 = 0.f, p1 = 0.f;
#pragma unroll
        for (int f = 0; f < 32; ++f) {
            float rv = rbuf[wave][g][f];
            p0 = fmaf(rv, w2s[f * 16 + 2 * m], p0);
            p1 = fmaf(rv, w2s[f * 16 + 2 * m + 1], p1);
        }
        __builtin_amdgcn_sched_barrier(0);
        *(float2*)&gp[(size_t)node * 16 + 2 * m] = make_float2(p0, p1);
    }
}

// ---------------------------------------------------------------------------
// Combine the 4 per-slice GEMM2 partials + dis scale, in place into plane 0
// (each thread reads planes 0..3 at index i and writes plane0[i]: no cross-
// thread overlap). g2 final = dis[n] * sum_s partial_s[n][c].
// ---------------------------------------------------------------------------
__global__ __launch_bounds__(256) void g2_reduce(float* __restrict__ g2p,
                                                 const float* __restrict__ dis) {
    int i = blockIdx.x * 256 + threadIdx.x;   // one float4 (4 classes)
    if (i >= N_NODES * 4) return;
    const size_t PS = (size_t)N_NODES * 16 / 4;  // plane stride in float4
    const float4* p = (const float4*)g2p;
    float4 a = p[i];
    float4 b = p[i + PS];
    float4 c = p[i + 2 * PS];
    float4 d = p[i + 3 * PS];
    float dv = dis[i >> 2];
    float4 r;
    r.x = dv * ((a.x + b.x) + (c.x + d.x));
    r.y = dv * ((a.y + b.y) + (c.y + d.y));
    r.z = dv * ((a.z + b.z) + (c.z + d.z));
    r.w = dv * ((a.w + b.w) + (c.w + d.w));
    ((float4*)g2p)[i] = r;
}

// ---------------------------------------------------------------------------
// Aggregation 2 + bias + logits + softmax. 16 lanes per node, unroll 8.
// g2 (3.2 MB) is per-XCD L2-resident by size already.
// ---------------------------------------------------------------------------
__global__ __launch_bounds__(256) void agg2_softmax(const float* __restrict__ g2,
                                                    const int* __restrict__ rs,
                                                    const int* __restrict__ re,
                                                    const unsigned short* __restrict__ csr_src,
                                                    const float* __restrict__ dis,
                                                    const float* __restrict__ b2,
                                                    float* __restrict__ out) {
    int tid = threadIdx.x;
    int node = blockIdx.x * 16 + (tid >> 4);
    int c = tid & 15;
    float acc0 = g2[(size_t)node * N_CLASSES + c];
    float acc1 = 0.f, acc2 = 0.f, acc3 = 0.f;
    float acc4 = 0.f, acc5 = 0.f, acc6 = 0.f, acc7 = 0.f;
    int e0 = rs[node], e1 = re[node];
    int e = e0;
    for (; e + 8 <= e1; e += 8) {
        int s0 = csr_src[e + 0], s1 = csr_src[e + 1], s2 = csr_src[e + 2], s3 = csr_src[e + 3];
        int s4 = csr_src[e + 4], s5 = csr_src[e + 5], s6 = csr_src[e + 6], s7 = csr_src[e + 7];
        acc0 += g2[(size_t)s0 * N_CLASSES + c];
        acc1 += g2[(size_t)s1 * N_CLASSES + c];
        acc2 += g2[(size_t)s2 * N_CLASSES + c];
        acc3 += g2[(size_t)s3 * N_CLASSES + c];
        acc4 += g2[(size_t)s4 * N_CLASSES + c];
        acc5 += g2[(size_t)s5 * N_CLASSES + c];
        acc6 += g2[(size_t)s6 * N_CLASSES + c];
        acc7 += g2[(size_t)s7 * N_CLASSES + c];
    }
    for (; e < e1; ++e) {
        int s = csr_src[e];
        acc0 += g2[(size_t)s * N_CLASSES + c];
    }
    acc0 = ((acc0 + acc1) + (acc2 + acc3)) + ((acc4 + acc5) + (acc6 + acc7));
    float logit = fmaf(dis[node], acc0, b2[c]);
    out[(size_t)node * N_CLASSES + c] = logit;
    float m = logit;
    for (int off = 8; off; off >>= 1) m = fmaxf(m, __shfl_xor(m, off));
    float ex = expf(logit - m);
    float s = ex;
    for (int off = 8; off; off >>= 1) s += __shfl_xor(s, off);
    out[(size_t)N_NODES * N_CLASSES + (size_t)node * N_CLASSES + c] = ex / s;
}

// ---------------------------------------------------------------------------

extern "C" void kernel_launch(void* const* d_in, const int* in_sizes, int n_in,
                              void* d_out, int out_size, void* d_ws, size_t ws_size,
                              hipStream_t stream) {
    const float* x  = (const float*)d_in[0];
    const int*   ei = (const int*)d_in[1];
    const float* W1 = (const float*)d_in[2];
    const float* b1 = (const float*)d_in[3];
    const float* W2 = (const float*)d_in[4];
    const float* b2 = (const float*)d_in[5];
    float* out = (float*)d_out;

    char* ws = (char*)d_ws;
    size_t off = 0;
    auto alloc = [&](size_t bytes) -> char* {
        char* p = ws + off;
        off = (off + bytes + 511) & ~(size_t)511;
        return p;
    };
    int*   cursor   = (int*)alloc(256 * 4);
    float* dis      = (float*)alloc(N_NODES * 4);
    int*   rs       = (int*)alloc(N_NODES * 4);
    int*   re       = (int*)alloc(N_NODES * 4);
    unsigned short* w1t = (unsigned short*)alloc((size_t)HIDDEN * IN_FEAT * 2);
    unsigned short* csr_src = (unsigned short*)alloc((size_t)NBKT * BCAP * 2);  // holey
    unsigned int* g1 = (unsigned int*)alloc((size_t)N_NODES * 64 * 4);          // slice-major: 4 x [N][16dw]
    float* g2p      = (float*)alloc(4 * (size_t)N_NODES * N_CLASSES * 4);       // per-slice GEMM2 partials
    // sorted edges (196*10240*4 = 8.0MB) alias g1's slab (12.8MB): dead before gemm1.
    unsigned int* sorted = (unsigned int*)g1;
    (void)ws_size; (void)in_sizes; (void)n_in; (void)out_size;

    const int* src = ei;
    const int* dst = ei + N_EDGES;

    hipMemsetAsync(cursor, 0, 256 * 4, stream);
    scatter_edges2<<<NCHK, 256, 0, stream>>>(src, dst, cursor, sorted, W1, w1t);
    build_csr2<<<NBKT, 256, 0, stream>>>(sorted, cursor, rs, re, dis, csr_src);

    gemm1_mfma<<<(N_NODES + 63) / 64, 256, 0, stream>>>(x, w1t, dis, g1);
    agg1_sliced<<<NBKT * 16, 256, 0, stream>>>((const uint2*)g1, rs, re, csr_src, dis, b1, W2, g2p);
    g2_reduce<<<(N_NODES * 4 + 255) / 256, 256, 0, stream>>>(g2p, dis);
    agg2_softmax<<<N_NODES / 16, 256, 0, stream>>>(g2p, rs, re, csr_src, dis, b2, out);
}

// Round 2
// 222.951 us; speedup vs baseline: 1.0751x; 1.0554x over previous
//
#include <hip/hip_runtime.h>
#include <hip/hip_bf16.h>
#include <math.h>

#define N_NODES 50000
#define N_EDGES 1600000
#define IN_FEAT 256
#define HIDDEN 128
#define N_CLASSES 16

#define ECHUNK 8192
#define NCHK 196    // ceil(1600000/8192)
#define NBKT 196    // ceil(50000/256) buckets of 256 nodes
#define BCAP 10240  // per-bucket capacity: mean 8192, std ~90 -> +23 sigma

typedef __attribute__((ext_vector_type(8))) short short8;   // 8 bf16 (A/B frag)
typedef __attribute__((ext_vector_type(4))) float floatx4;  // C/D frag

// bf16 round-to-nearest-even (scalar integer path)
__device__ __forceinline__ unsigned short f2bf(float f) {
    unsigned u = __float_as_uint(f);
    return (unsigned short)((u + 0x7fffu + ((u >> 16) & 1u)) >> 16);
}

// HW packed fp32->bf16x2
__device__ __forceinline__ unsigned pk2bf(float a, float b) {
    __hip_bfloat162 h = __float22bfloat162_rn(make_float2(a, b));
    union { __hip_bfloat162 h; unsigned u; } cv;
    cv.h = h;
    return cv.u;
}

__device__ __forceinline__ float bflo(unsigned u) { return __uint_as_float(u << 16); }
__device__ __forceinline__ float bfhi(unsigned u) { return __uint_as_float(u & 0xffff0000u); }

// ---------------------------------------------------------------------------
// Prep: fixed-capacity buckets. scatter: LDS-count -> 1 global atomic per
// (block,bucket) -> local scatter. Blocks 0..127 also transpose W1 -> w1t.
// ---------------------------------------------------------------------------
__global__ __launch_bounds__(256) void scatter_edges2(const int* __restrict__ src,
                                                      const int* __restrict__ dst,
                                                      int* __restrict__ cursor,   // [256], zeroed
                                                      unsigned int* __restrict__ sorted,
                                                      const float* __restrict__ W1,
                                                      unsigned short* __restrict__ w1t) {
    __shared__ int hloc[256];
    int t = threadIdx.x;
    hloc[t] = 0;
    if (blockIdx.x < HIDDEN)
        w1t[blockIdx.x * IN_FEAT + t] = f2bf(W1[t * HIDDEN + blockIdx.x]);
    __syncthreads();
    int base = blockIdx.x * ECHUNK;
    int end = min(base + ECHUNK, N_EDGES);
    for (int i = base + t; i < end; i += 256)
        atomicAdd(&hloc[dst[i] >> 8], 1);
    __syncthreads();
    int cnt = hloc[t];
    int lbase = t * BCAP + atomicAdd(&cursor[t], cnt);  // block's base in bucket t
    __syncthreads();
    hloc[t] = lbase;  // reuse as local cursor
    __syncthreads();
    for (int i = base + t; i < end; i += 256) {
        int d = dst[i];
        int s = src[i];
        int pos = atomicAdd(&hloc[d >> 8], 1);
        sorted[pos] = ((unsigned)d << 16) | (unsigned)s;
    }
}

__global__ __launch_bounds__(256) void build_csr2(const unsigned int* __restrict__ sorted,
                                                  const int* __restrict__ cursor,
                                                  int* __restrict__ rs,
                                                  int* __restrict__ re,
                                                  float* __restrict__ dis,
                                                  unsigned short* __restrict__ csr_src) {
    __shared__ int cnt[256];
    __shared__ int roff[256];
    int t = threadIdx.x;
    int bkt = blockIdx.x;
    int ebase = bkt * BCAP;
    int eend = ebase + cursor[bkt];
    cnt[t] = 0;
    __syncthreads();
    for (int i = ebase + t; i < eend; i += 256)
        atomicAdd(&cnt[(sorted[i] >> 16) & 255], 1);
    __syncthreads();
    int v = cnt[t];
    roff[t] = v;
    __syncthreads();
    for (int off = 1; off < 256; off <<= 1) {
        int x = (t >= off) ? roff[t - off] : 0;
        __syncthreads();
        roff[t] += x;
        __syncthreads();
    }
    int excl = roff[t] - v;
    int node = bkt * 256 + t;
    if (node < N_NODES) {
        rs[node] = ebase + excl;
        re[node] = ebase + excl + v;
        dis[node] = 1.0f / sqrtf((float)(v + 1));  // +1 self loop
    }
    __syncthreads();
    cnt[t] = ebase + excl;  // reuse as cursor
    __syncthreads();
    for (int i = ebase + t; i < eend; i += 256) {
        unsigned e = sorted[i];
        int pos = atomicAdd(&cnt[(e >> 16) & 255], 1);
        csr_src[pos] = (unsigned short)(e & 0xffffu);
    }
}

// ---------------------------------------------------------------------------
// GEMM1 via MFMA with LDS-staged A (global_load_lds, width 16).
// Block 64 rows x 128 cols, 4 waves (2x2); wave = 32 rows x 64 cols.
// Output layout is SLICE-MAJOR: g1[slice][node][16 dwords] with slice =
// col>>5, so each 32-feature slice is a contiguous 3.2 MB plane (fits one
// XCD's 4 MB L2; slices never share a 128B L2 line).
// ---------------------------------------------------------------------------
#define XCH 260   // dwords per 8-row chunk: 8*32 + 4 pad

__global__ __launch_bounds__(256) void gemm1_mfma(const float* __restrict__ x,
                                                  const unsigned short* __restrict__ w1t,
                                                  const float* __restrict__ dis,
                                                  unsigned int* __restrict__ g1) {
    __shared__ float xs[2][8 * XCH];   // 2 x 8320 B
    int tid = threadIdx.x;
    int w = tid >> 6;
    int lane = tid & 63;
    int quad = lane >> 4;
    int c = lane & 15;
    int row_base = blockIdx.x * 64;
    int wrow = (w >> 1) * 32;        // wave's row offset in tile
    int col_base = (w & 1) * 64;

    // staging: wave w stages chunks 2w, 2w+1 (rows 16w..16w+15 of the tile)
    int st_row = min(row_base + 16 * w + (lane >> 3), N_NODES - 1);       // chunk 2w
    int st_row2 = min(row_base + 16 * w + 8 + (lane >> 3), N_NODES - 1);  // chunk 2w+1
    const float* gp1 = x + (size_t)st_row * IN_FEAT + (lane & 7) * 4;
    const float* gp2 = x + (size_t)st_row2 * IN_FEAT + (lane & 7) * 4;

    floatx4 acc[2][4] = {};
    const unsigned short* bp[4];
#pragma unroll
    for (int nt = 0; nt < 4; ++nt)
        bp[nt] = w1t + (size_t)(col_base + nt * 16 + c) * IN_FEAT + quad * 8;

    // A-frag ds_read offsets (dwords) for rt=0,1
    int dwoff[2];
#pragma unroll
    for (int rt = 0; rt < 2; ++rt) {
        int rit = wrow + rt * 16 + c;
        dwoff[rt] = (rit >> 3) * XCH + (rit & 7) * 32 + quad * 8;
    }

#define STAGE(buf, k0)                                                                  \
    do {                                                                                \
        __builtin_amdgcn_global_load_lds(                                               \
            (const __attribute__((address_space(1))) void*)(gp1 + (k0)),                \
            (__attribute__((address_space(3))) void*)&xs[buf][(2 * w) * XCH], 16, 0, 0);\
        __builtin_amdgcn_global_load_lds(                                               \
            (const __attribute__((address_space(1))) void*)(gp2 + (k0)),                \
            (__attribute__((address_space(3))) void*)&xs[buf][(2 * w + 1) * XCH], 16, 0, 0);\
    } while (0)

    STAGE(0, 0);
    __syncthreads();

    int buf = 0;
#pragma unroll
    for (int kk = 0; kk < 8; ++kk) {
        if (kk < 7) STAGE(buf ^ 1, (kk + 1) * 32);
        // B frags for this k-step (global, L2-hot)
        short8 b[4];
#pragma unroll
        for (int nt = 0; nt < 4; ++nt)
            b[nt] = *(const short8*)(bp[nt] + kk * 32);
        // A frags from LDS, convert fp32 -> bf16
        short8 a[2];
#pragma unroll
        for (int rt = 0; rt < 2; ++rt) {
            float4 f0 = *(const float4*)&xs[buf][dwoff[rt]];
            float4 f1 = *(const float4*)&xs[buf][dwoff[rt] + 4];
            union { short8 s; unsigned u[4]; } au;
            au.u[0] = pk2bf(f0.x, f0.y);
            au.u[1] = pk2bf(f0.z, f0.w);
            au.u[2] = pk2bf(f1.x, f1.y);
            au.u[3] = pk2bf(f1.z, f1.w);
            a[rt] = au.s;
        }
#pragma unroll
        for (int rt = 0; rt < 2; ++rt)
#pragma unroll
            for (int nt = 0; nt < 4; ++nt)
                acc[rt][nt] = __builtin_amdgcn_mfma_f32_16x16x32_bf16(a[rt], b[nt], acc[rt][nt], 0, 0, 0);
        __syncthreads();   // drains stage vmcnt + protects buf reuse
        buf ^= 1;
    }
#undef STAGE

    // Epilogue: dis scale, pair adjacent cols via shfl, pack bf16x2, store
    // into slice-major layout. C/D layout: col = lane&15, row = quad*4 + reg.
    bool evenlane = (lane & 1) == 0;
#pragma unroll
    for (int rt = 0; rt < 2; ++rt) {
#pragma unroll
        for (int reg = 0; reg < 4; ++reg) {
            int row = row_base + wrow + rt * 16 + quad * 4 + reg;
            float dv = dis[min(row, N_NODES - 1)];
#pragma unroll
            for (int nt = 0; nt < 4; ++nt) {
                float v = acc[rt][nt][reg] * dv;
                float vo = __shfl_xor(v, 1);
                if (evenlane && row < N_NODES) {
                    unsigned pkd = (unsigned)f2bf(v) | ((unsigned)f2bf(vo) << 16);
                    int col = col_base + nt * 16 + c;  // even
                    g1[(size_t)(col >> 5) * (N_NODES * 16) + (size_t)row * 16 + ((col & 31) >> 1)] = pkd;
                }
            }
        }
    }
}

// ---------------------------------------------------------------------------
// Aggregation 1 + bias + ReLU + per-slice GEMM2 partial. Feature-sliced,
// XCD-pinned (blockIdx&7 -> slice plane, 3.2MB, L2-resident per XCD).
// v2: 4-lane groups (16 nodes/wave), dwordx4 gathers, explicit ping-pong
// register double-buffer (A/B batches of 4 edges) + index prefetch issued
// BEFORE the gathers it trails, so steady-state waits are vmcnt(5), never
// a full drain. Index loaded once per lane, distributed via quad shfl.
// ---------------------------------------------------------------------------
__global__ __launch_bounds__(256) void agg1_sliced(const uint4* __restrict__ g1,
                                                   const int* __restrict__ rs,
                                                   const int* __restrict__ re,
                                                   const unsigned short* __restrict__ csr_src,
                                                   const float* __restrict__ dis,
                                                   const float* __restrict__ b1,
                                                   const float* __restrict__ W2,
                                                   float* __restrict__ g2p) {
    __shared__ float w2s[32 * 16];      // this slice's W2 rows (2 KB)
    __shared__ float rbuf[4][16][36];   // per wave/group r vector (32 feats + pad)
    int tid = threadIdx.x;
    int bi = blockIdx.x;
    int bucket = bi >> 4;               // 196
    int xcd = bi & 7;
    int slice = xcd >> 1;               // XCD pair {2s,2s+1} -> slice s
    int quarter = ((bi >> 3) & 1) * 2 + (xcd & 1);

    for (int i = tid; i < 512; i += 256) w2s[i] = W2[slice * 512 + i];
    __syncthreads();

    int wave = tid >> 6, lane = tid & 63;
    int g = lane >> 2, m4 = lane & 3;   // group g owns a node; lane m4 covers feats 8*m4..8*m4+7
    int qb = lane & ~3;                 // quad base lane
    const uint4* plane = g1 + (size_t)slice * (N_NODES * 4);
    float* gp = g2p + (size_t)slice * ((size_t)N_NODES * 16);
    int node = bucket * 256 + quarter * 64 + wave * 16 + g;
    bool alive = (node < N_NODES);

#define ACC8(u) do { a0 += bflo((u).x); a1 += bfhi((u).x); a2 += bflo((u).y); a3 += bfhi((u).y); \
                     a4 += bflo((u).z); a5 += bfhi((u).z); a6 += bflo((u).w); a7 += bfhi((u).w); } while (0)
#define LDB(ii, U0, U1, U2, U3) do {                        \
        int j0 = __shfl((ii), qb + 0);                      \
        int j1 = __shfl((ii), qb + 1);                      \
        int j2 = __shfl((ii), qb + 2);                      \
        int j3 = __shfl((ii), qb + 3);                      \
        U0 = plane[(size_t)j0 * 4 + m4];                    \
        U1 = plane[(size_t)j1 * 4 + m4];                    \
        U2 = plane[(size_t)j2 * 4 + m4];                    \
        U3 = plane[(size_t)j3 * 4 + m4];                    \
    } while (0)

    if (alive) {
        uint4 su = plane[(size_t)node * 4 + m4];   // self loop (g1 carries dis[src])
        float a0 = bflo(su.x), a1 = bfhi(su.x), a2 = bflo(su.y), a3 = bfhi(su.y);
        float a4 = bflo(su.z), a5 = bfhi(su.z), a6 = bflo(su.w), a7 = bfhi(su.w);
        int e = rs[node], e1v = re[node];
        int rem = e1v - e;

        if (rem >= 4) {
            uint4 A0, A1, A2, A3, B0, B1, B2, B3;
            int iC = csr_src[e + m4];        // idx batch 0
            int iN = csr_src[e + 4 + m4];    // idx batch 1 (prefetch; harmless overread)
            LDB(iC, A0, A1, A2, A3);
            e += 4; rem -= 4;
            while (rem >= 8) {
                iC = iN;
                iN = csr_src[e + 4 + m4];    // prefetch batch k+2 idx BEFORE B gathers
                LDB(iC, B0, B1, B2, B3);
                __builtin_amdgcn_sched_barrier(0);
                ACC8(A0); ACC8(A1); ACC8(A2); ACC8(A3);
                iC = iN;
                iN = csr_src[e + 8 + m4];
                LDB(iC, A0, A1, A2, A3);
                __builtin_amdgcn_sched_barrier(0);
                ACC8(B0); ACC8(B1); ACC8(B2); ACC8(B3);
                e += 8; rem -= 8;
            }
            if (rem >= 4) {
                iC = iN;
                LDB(iC, B0, B1, B2, B3);
                __builtin_amdgcn_sched_barrier(0);
                ACC8(A0); ACC8(A1); ACC8(A2); ACC8(A3);
                ACC8(B0); ACC8(B1); ACC8(B2); ACC8(B3);
                e += 4; rem -= 4;
            } else {
                ACC8(A0); ACC8(A1); ACC8(A2); ACC8(A3);
            }
        }
        while (rem > 0) {   // tail 0..3 edges, group-uniform index (broadcast load)
            int j = csr_src[e];
            uint4 u = plane[(size_t)j * 4 + m4];
            ACC8(u);
            ++e; --rem;
        }

        // bias + ReLU, publish r (lane owns feats 8*m4..8*m4+7)
        float dv = dis[node];
        float4 bb0 = *(const float4*)&b1[slice * 32 + 8 * m4];
        float4 bb1 = *(const float4*)&b1[slice * 32 + 8 * m4 + 4];
        float4 r0, r1;
        r0.x = fmaxf(fmaf(dv, a0, bb0.x), 0.f);
        r0.y = fmaxf(fmaf(dv, a1, bb0.y), 0.f);
        r0.z = fmaxf(fmaf(dv, a2, bb0.z), 0.f);
        r0.w = fmaxf(fmaf(dv, a3, bb0.w), 0.f);
        r1.x = fmaxf(fmaf(dv, a4, bb1.x), 0.f);
        r1.y = fmaxf(fmaf(dv, a5, bb1.y), 0.f);
        r1.z = fmaxf(fmaf(dv, a6, bb1.z), 0.f);
        r1.w = fmaxf(fmaf(dv, a7, bb1.w), 0.f);
        *(float4*)&rbuf[wave][g][8 * m4] = r0;
        *(float4*)&rbuf[wave][g][8 * m4 + 4] = r1;
    }
    __builtin_amdgcn_sched_barrier(0);   // wave-synchronous LDS: keep reads after writes
    if (alive) {
        // GEMM2 partial: lane m4 computes classes 4*m4..4*m4+3 over all 32 feats
        float p0 = 0.f, p1 = 0.f, p2 = 0.f, p3 = 0.f;
#pragma unroll
        for (int fb = 0; fb < 8; ++fb) {
            float4 rv = *(const float4*)&rbuf[wave][g][fb * 4];
            float4 w0 = *(const float4*)&w2s[(fb * 4 + 0) * 16 + 4 * m4];
            float4 w1 = *(const float4*)&w2s[(fb * 4 + 1) * 16 + 4 * m4];
            float4 w2 = *(const float4*)&w2s[(fb * 4 + 2) * 16 + 4 * m4];
            float4 w3 = *(const float4*)&w2s[(fb * 4 + 3) * 16 + 4 * m4];
            p0 = fmaf(rv.x, w0.x, p0); p1 = fmaf(rv.x, w0.y, p1);
            p2 = fmaf(rv.x, w0.z, p2); p3 = fmaf(rv.x, w0.w, p3);
            p0 = fmaf(rv.y, w1.x, p0); p1 = fmaf(rv.y, w1.y, p1);
            p2 = fmaf(rv.y, w1.z, p2); p3 = fmaf(rv.y, w1.w, p3);
            p0 = fmaf(rv.z, w2.x, p0); p1 = fmaf(rv.z, w2.y, p1);
            p2 = fmaf(rv.z, w2.z, p2); p3 = fmaf(rv.z, w2.w, p3);
            p0 = fmaf(rv.w, w3.x, p0); p1 = fmaf(rv.w, w3.y, p1);
            p2 = fmaf(rv.w, w3.z, p2); p3 = fmaf(rv.w, w3.w, p3);
        }
        float4 pv; pv.x = p0; pv.y = p1; pv.z = p2; pv.w = p3;
        *(float4*)&gp[(size_t)node * 16 + 4 * m4] = pv;
    }
#undef LDB
#undef ACC8
}

// ---------------------------------------------------------------------------
// Combine the 4 per-slice GEMM2 partials + dis scale, in place into plane 0.
// ---------------------------------------------------------------------------
__global__ __launch_bounds__(256) void g2_reduce(float* __restrict__ g2p,
                                                 const float* __restrict__ dis) {
    int i = blockIdx.x * 256 + threadIdx.x;   // one float4 (4 classes)
    if (i >= N_NODES * 4) return;
    const size_t PS = (size_t)N_NODES * 16 / 4;  // plane stride in float4
    const float4* p = (const float4*)g2p;
    float4 a = p[i];
    float4 b = p[i + PS];
    float4 c = p[i + 2 * PS];
    float4 d = p[i + 3 * PS];
    float dv = dis[i >> 2];
    float4 r;
    r.x = dv * ((a.x + b.x) + (c.x + d.x));
    r.y = dv * ((a.y + b.y) + (c.y + d.y));
    r.z = dv * ((a.z + b.z) + (c.z + d.z));
    r.w = dv * ((a.w + b.w) + (c.w + d.w));
    ((float4*)g2p)[i] = r;
}

// ---------------------------------------------------------------------------
// Aggregation 2 + bias + logits + softmax. v2: same pipelined-gather
// structure as agg1 (4-lane groups, float4 gathers, ping-pong batches,
// early index prefetch). g2 (3.2 MB) is L2-resident per XCD by size.
// ---------------------------------------------------------------------------
__global__ __launch_bounds__(256) void agg2_softmax(const float4* __restrict__ g2,
                                                    const int* __restrict__ rs,
                                                    const int* __restrict__ re,
                                                    const unsigned short* __restrict__ csr_src,
                                                    const float* __restrict__ dis,
                                                    const float* __restrict__ b2,
                                                    float* __restrict__ out) {
    int tid = threadIdx.x;
    int wave = tid >> 6, lane = tid & 63;
    int g = lane >> 2, m4 = lane & 3;   // group owns a node; lane m4 covers classes 4*m4..4*m4+3
    int qb = lane & ~3;
    int node = blockIdx.x * 64 + wave * 16 + g;
    if (node >= N_NODES) return;

    float4 acc = g2[(size_t)node * 4 + m4];   // self loop

#define ACC4(u) do { acc.x += (u).x; acc.y += (u).y; acc.z += (u).z; acc.w += (u).w; } while (0)
#define LDB4(ii, U0, U1, U2, U3) do {                       \
        int j0 = __shfl((ii), qb + 0);                      \
        int j1 = __shfl((ii), qb + 1);                      \
        int j2 = __shfl((ii), qb + 2);                      \
        int j3 = __shfl((ii), qb + 3);                      \
        U0 = g2[(size_t)j0 * 4 + m4];                       \
        U1 = g2[(size_t)j1 * 4 + m4];                       \
        U2 = g2[(size_t)j2 * 4 + m4];                       \
        U3 = g2[(size_t)j3 * 4 + m4];                       \
    } while (0)

    int e = rs[node], e1v = re[node];
    int rem = e1v - e;
    if (rem >= 4) {
        float4 A0, A1, A2, A3, B0, B1, B2, B3;
        int iC = csr_src[e + m4];
        int iN = csr_src[e + 4 + m4];
        LDB4(iC, A0, A1, A2, A3);
        e += 4; rem -= 4;
        while (rem >= 8) {
            iC = iN;
            iN = csr_src[e + 4 + m4];
            LDB4(iC, B0, B1, B2, B3);
            __builtin_amdgcn_sched_barrier(0);
            ACC4(A0); ACC4(A1); ACC4(A2); ACC4(A3);
            iC = iN;
            iN = csr_src[e + 8 + m4];
            LDB4(iC, A0, A1, A2, A3);
            __builtin_amdgcn_sched_barrier(0);
            ACC4(B0); ACC4(B1); ACC4(B2); ACC4(B3);
            e += 8; rem -= 8;
        }
        if (rem >= 4) {
            iC = iN;
            LDB4(iC, B0, B1, B2, B3);
            __builtin_amdgcn_sched_barrier(0);
            ACC4(A0); ACC4(A1); ACC4(A2); ACC4(A3);
            ACC4(B0); ACC4(B1); ACC4(B2); ACC4(B3);
            e += 4; rem -= 4;
        } else {
            ACC4(A0); ACC4(A1); ACC4(A2); ACC4(A3);
        }
    }
    while (rem > 0) {
        int j = csr_src[e];
        float4 u = g2[(size_t)j * 4 + m4];
        ACC4(u);
        ++e; --rem;
    }
#undef LDB4
#undef ACC4

    float dv = dis[node];
    float4 bb = *(const float4*)&b2[4 * m4];
    float4 lg;
    lg.x = fmaf(dv, acc.x, bb.x);
    lg.y = fmaf(dv, acc.y, bb.y);
    lg.z = fmaf(dv, acc.z, bb.z);
    lg.w = fmaf(dv, acc.w, bb.w);
    ((float4*)out)[(size_t)node * 4 + m4] = lg;

    // softmax over 16 classes = 4 lanes x 4
    float m = fmaxf(fmaxf(lg.x, lg.y), fmaxf(lg.z, lg.w));
    m = fmaxf(m, __shfl_xor(m, 1));
    m = fmaxf(m, __shfl_xor(m, 2));
    float4 ex;
    ex.x = expf(lg.x - m); ex.y = expf(lg.y - m);
    ex.z = expf(lg.z - m); ex.w = expf(lg.w - m);
    float s = (ex.x + ex.y) + (ex.z + ex.w);
    s += __shfl_xor(s, 1);
    s += __shfl_xor(s, 2);
    float inv = 1.0f / s;
    ex.x *= inv; ex.y *= inv; ex.z *= inv; ex.w *= inv;
    ((float4*)out)[(size_t)N_NODES * 4 + (size_t)node * 4 + m4] = ex;
}

// ---------------------------------------------------------------------------

extern "C" void kernel_launch(void* const* d_in, const int* in_sizes, int n_in,
                              void* d_out, int out_size, void* d_ws, size_t ws_size,
                              hipStream_t stream) {
    const float* x  = (const float*)d_in[0];
    const int*   ei = (const int*)d_in[1];
    const float* W1 = (const float*)d_in[2];
    const float* b1 = (const float*)d_in[3];
    const float* W2 = (const float*)d_in[4];
    const float* b2 = (const float*)d_in[5];
    float* out = (float*)d_out;

    char* ws = (char*)d_ws;
    size_t off = 0;
    auto alloc = [&](size_t bytes) -> char* {
        char* p = ws + off;
        off = (off + bytes + 511) & ~(size_t)511;
        return p;
    };
    int*   cursor   = (int*)alloc(256 * 4);
    float* dis      = (float*)alloc(N_NODES * 4);
    int*   rs       = (int*)alloc(N_NODES * 4);
    int*   re       = (int*)alloc(N_NODES * 4);
    unsigned short* w1t = (unsigned short*)alloc((size_t)HIDDEN * IN_FEAT * 2);
    unsigned short* csr_src = (unsigned short*)alloc((size_t)NBKT * BCAP * 2);  // holey
    unsigned int* g1 = (unsigned int*)alloc((size_t)N_NODES * 64 * 4);          // slice-major: 4 x [N][16dw]
    float* g2p      = (float*)alloc(4 * (size_t)N_NODES * N_CLASSES * 4);       // per-slice GEMM2 partials
    // sorted edges (196*10240*4 = 8.0MB) alias g1's slab (12.8MB): dead before gemm1.
    unsigned int* sorted = (unsigned int*)g1;
    (void)ws_size; (void)in_sizes; (void)n_in; (void)out_size;

    const int* src = ei;
    const int* dst = ei + N_EDGES;

    hipMemsetAsync(cursor, 0, 256 * 4, stream);
    scatter_edges2<<<NCHK, 256, 0, stream>>>(src, dst, cursor, sorted, W1, w1t);
    build_csr2<<<NBKT, 256, 0, stream>>>(sorted, cursor, rs, re, dis, csr_src);

    gemm1_mfma<<<(N_NODES + 63) / 64, 256, 0, stream>>>(x, w1t, dis, g1);
    agg1_sliced<<<NBKT * 16, 256, 0, stream>>>((const uint4*)g1, rs, re, csr_src, dis, b1, W2, g2p);
    g2_reduce<<<(N_NODES * 4 + 255) / 256, 256, 0, stream>>>(g2p, dis);
    agg2_softmax<<<N_NODES / 64 + 1, 256, 0, stream>>>((const float4*)g2p, rs, re, csr_src, dis, b2, out);
}